// Round 1
// baseline (78.884 us; speedup 1.0000x reference)
//
#include <hip/hip_runtime.h>
#include <math.h>

namespace {
constexpr int N_TOK = 16384;
constexpr int DIM   = 1024;
constexpr int NCLAN = 32;
constexpr int FPC_  = 64;
constexpr int HID   = 128;   // 2*FPC
constexpr int FTOT  = NCLAN * FPC_;   // 2048
constexpr float EPS = 1e-5f;
}

// ---------------- routing: per-token argmax, global min ----------------
__global__ void clan_min_kernel(const float* __restrict__ xc, int* __restrict__ sel) {
    int i = blockIdx.x * blockDim.x + threadIdx.x;
    int bi = 0x7f7f7f7f;
    if (i < N_TOK) {
        const float* row = xc + (size_t)i * NCLAN;
        float best = row[0]; bi = 0;
        #pragma unroll
        for (int c = 1; c < NCLAN; ++c) { float v = row[c]; if (v > best) { best = v; bi = c; } }
    }
    // wave-level min to cut atomics 64x
    #pragma unroll
    for (int off = 32; off > 0; off >>= 1) bi = min(bi, __shfl_down(bi, off));
    if ((threadIdx.x & 63) == 0) atomicMin(sel, bi);
}

// ---------------- compact selected token indices ----------------
__global__ void compact_kernel(const float* __restrict__ xc, const int* __restrict__ sel_p,
                               int* __restrict__ cnt, int* __restrict__ list) {
    int i = blockIdx.x * blockDim.x + threadIdx.x;
    if (i >= N_TOK) return;
    const int sel = *sel_p;
    const float* row = xc + (size_t)i * NCLAN;
    float best = row[0]; int bi = 0;
    #pragma unroll
    for (int c = 1; c < NCLAN; ++c) { float v = row[c]; if (v > best) { best = v; bi = c; } }
    if (bi == sel) { int p = atomicAdd(cnt, 1); list[p] = i; }
}

// ---------------- per-token expert MLP body ----------------
__device__ __forceinline__ void expert_token(
    int tok, int sel,
    const float* __restrict__ x, const float* __restrict__ W1, const float* __restrict__ b1,
    const float* __restrict__ gamma, const float* __restrict__ beta,
    const float* __restrict__ W2, const float* __restrict__ b2,
    float* __restrict__ out, float* __restrict__ xs, float* __restrict__ rbuf,
    float* __restrict__ red)
{
    const int t = threadIdx.x;                       // 0..127, t == hidden channel
    // stage x row (1024 f32 = 4KB) into LDS, float4-vectorized, coalesced
    const float4* __restrict__ xr = (const float4*)(x + (size_t)tok * DIM);
    ((float4*)xs)[t]       = xr[t];
    ((float4*)xs)[t + HID] = xr[t + HID];
    __syncthreads();

    // h[t] = sum_d x[d] * W1[sel][d][t] + b1[sel][t]; W1 reads coalesced (stride H per d)
    const float* __restrict__ w1 = W1 + (size_t)sel * DIM * HID + t;
    float acc = b1[sel * HID + t];
    #pragma unroll 8
    for (int d = 0; d < DIM; ++d) acc = fmaf(xs[d], w1[d * HID], acc);

    // LayerNorm over 128 channels: shfl reduce within each wave, combine 2 waves via LDS
    float s = acc, sq = acc * acc;
    #pragma unroll
    for (int off = 32; off > 0; off >>= 1) { s += __shfl_down(s, off); sq += __shfl_down(sq, off); }
    const int wv = t >> 6;
    if ((t & 63) == 0) { red[wv * 2] = s; red[wv * 2 + 1] = sq; }
    __syncthreads();
    const float mu  = (red[0] + red[2]) * (1.0f / HID);
    const float msq = (red[1] + red[3]) * (1.0f / HID);
    const float inv = rsqrtf(msq - mu * mu + EPS);
    float r = (acc - mu) * inv * gamma[sel * HID + t] + beta[sel * HID + t];
    rbuf[t] = fmaxf(r, 0.0f);
    __syncthreads();

    // out[f] = sum_h relu_h * W2[sel][h][f] + b2[sel][f]; threads 0..63
    if (t < FPC_) {
        const float* __restrict__ w2 = W2 + (size_t)sel * HID * FPC_ + t;
        float o = b2[sel * FPC_ + t];
        #pragma unroll 8
        for (int h = 0; h < HID; ++h) o = fmaf(rbuf[h], w2[h * FPC_], o);
        out[(size_t)tok * FTOT + sel * FPC_ + t] = o;
    }
    __syncthreads();   // protect xs/rbuf/red for next grid-stride iteration
}

__global__ __launch_bounds__(128) void expert_list_kernel(
    const float* __restrict__ x, const float* __restrict__ W1, const float* __restrict__ b1,
    const float* __restrict__ gamma, const float* __restrict__ beta,
    const float* __restrict__ W2, const float* __restrict__ b2,
    const int* __restrict__ sel_p, const int* __restrict__ cnt_p, const int* __restrict__ list,
    float* __restrict__ out)
{
    __shared__ float xs[DIM];
    __shared__ float rbuf[HID];
    __shared__ float red[4];
    const int sel = *sel_p;
    const int M   = *cnt_p;
    for (int i = blockIdx.x; i < M; i += gridDim.x) {
        expert_token(list[i], sel, x, W1, b1, gamma, beta, W2, b2, out, xs, rbuf, red);
    }
}

// fallback if ws too small for the list: every token gets a block, recompute argmax
__global__ __launch_bounds__(128) void expert_scan_kernel(
    const float* __restrict__ x, const float* __restrict__ xc,
    const float* __restrict__ W1, const float* __restrict__ b1,
    const float* __restrict__ gamma, const float* __restrict__ beta,
    const float* __restrict__ W2, const float* __restrict__ b2,
    const int* __restrict__ sel_p, float* __restrict__ out)
{
    __shared__ float xs[DIM];
    __shared__ float rbuf[HID];
    __shared__ float red[4];
    __shared__ int clan_sh;
    const int tok = blockIdx.x;
    if (threadIdx.x < 64) {
        const int c = threadIdx.x;
        float v = (c < NCLAN) ? xc[(size_t)tok * NCLAN + c] : -INFINITY;
        int idx = c;
        #pragma unroll
        for (int off = 32; off > 0; off >>= 1) {
            float ov = __shfl_down(v, off);
            int   oi = __shfl_down(idx, off);
            if (ov > v || (ov == v && oi < idx)) { v = ov; idx = oi; }
        }
        if (threadIdx.x == 0) clan_sh = idx;
    }
    __syncthreads();
    if (clan_sh != *sel_p) return;
    expert_token(tok, *sel_p, x, W1, b1, gamma, beta, W2, b2, out, xs, rbuf, red);
}

extern "C" void kernel_launch(void* const* d_in, const int* in_sizes, int n_in,
                              void* d_out, int out_size, void* d_ws, size_t ws_size,
                              hipStream_t stream) {
    const float* x     = (const float*)d_in[0];
    const float* xc    = (const float*)d_in[1];
    const float* W1    = (const float*)d_in[2];
    const float* b1    = (const float*)d_in[3];
    const float* gamma = (const float*)d_in[4];
    const float* beta  = (const float*)d_in[5];
    const float* W2    = (const float*)d_in[6];
    const float* b2    = (const float*)d_in[7];
    float* out = (float*)d_out;

    int* wsi   = (int*)d_ws;
    int* sel_p = wsi;
    int* cnt_p = wsi + 1;
    int* list  = wsi + 2;

    // zero the full output (only the selected 64-col block of selected rows is nonzero)
    hipMemsetAsync(d_out, 0, (size_t)out_size * sizeof(float), stream);
    hipMemsetAsync(sel_p, 0x7f, sizeof(int), stream);   // sel = 0x7f7f7f7f (big)
    hipMemsetAsync(cnt_p, 0, sizeof(int), stream);

    clan_min_kernel<<<(N_TOK + 255) / 256, 256, 0, stream>>>(xc, sel_p);

    const bool have_list = ws_size >= (size_t)(2 + N_TOK) * sizeof(int);
    if (have_list) {
        compact_kernel<<<(N_TOK + 255) / 256, 256, 0, stream>>>(xc, sel_p, cnt_p, list);
        expert_list_kernel<<<2048, 128, 0, stream>>>(x, W1, b1, gamma, beta, W2, b2,
                                                     sel_p, cnt_p, list, out);
    } else {
        expert_scan_kernel<<<N_TOK, 128, 0, stream>>>(x, xc, W1, b1, gamma, beta, W2, b2,
                                                      sel_p, out);
    }
}

// Round 2
// 53.640 us; speedup vs baseline: 1.4706x; 1.4706x over previous
//
#include <hip/hip_runtime.h>
#include <math.h>

namespace {
constexpr int N_TOK = 16384;
constexpr int DIM   = 1024;
constexpr int NCLAN = 32;
constexpr int FPC_  = 64;
constexpr int HID   = 128;            // 2*FPC
constexpr int FTOT  = NCLAN * FPC_;   // 2048
constexpr int ROW_F4 = FTOT / 4;      // 512 float4 per row
constexpr float EPS = 1e-5f;
}

// ---------------- pass 1: per-token argmax, global min -> sel ----------------
__global__ void clan_min_kernel(const float* __restrict__ xc, int* __restrict__ sel) {
    int i = blockIdx.x * blockDim.x + threadIdx.x;
    int bi = 0x7f7f7f7f;
    if (i < N_TOK) {
        const float* row = xc + (size_t)i * NCLAN;
        float best = row[0]; bi = 0;
        #pragma unroll
        for (int c = 1; c < NCLAN; ++c) { float v = row[c]; if (v > best) { best = v; bi = c; } }
    }
    #pragma unroll
    for (int off = 32; off > 0; off >>= 1) bi = min(bi, __shfl_down(bi, off));
    if ((threadIdx.x & 63) == 0) atomicMin(sel, bi);
}

// ---------------- pass 2: fused zero-fill + route + expert MLP ----------------
// One block (256 threads) per token row. Every block writes its full 8KB row.
// Selected blocks compute the MLP and substitute the 64-col block.
__global__ __launch_bounds__(256) void fused_fill_expert_kernel(
    const float* __restrict__ x, const float* __restrict__ xc,
    const float* __restrict__ W1, const float* __restrict__ b1,
    const float* __restrict__ gamma, const float* __restrict__ beta,
    const float* __restrict__ W2, const float* __restrict__ b2,
    const int* __restrict__ sel_p, float* __restrict__ out)
{
    __shared__ float xs[DIM];      // 4KB staged x row
    __shared__ float part[256];    // GEMV1 partials
    __shared__ float rbuf[HID];    // post-LN/ReLU activations
    __shared__ float obuf[FPC_];   // expert outputs
    __shared__ float red[4];       // LN cross-wave reduce
    __shared__ int   flag_sh;

    const int tok = blockIdx.x;
    const int t   = threadIdx.x;
    const int sel = *sel_p;

    // --- routing: does this token pick clan `sel`? (wave 0, first-occurrence argmax)
    if (t < 64) {
        float v = (t < NCLAN) ? xc[(size_t)tok * NCLAN + t] : -INFINITY;
        int idx = t;
        #pragma unroll
        for (int off = 32; off > 0; off >>= 1) {
            float ov = __shfl_down(v, off);
            int   oi = __shfl_down(idx, off);
            if (ov > v || (ov == v && oi < idx)) { v = ov; idx = oi; }
        }
        if (t == 0) flag_sh = (idx == sel) ? 1 : 0;
    }
    __syncthreads();
    const bool selected = (flag_sh != 0);   // block-uniform

    if (selected) {
        // stage x row: 256 threads x float4 = 4KB, coalesced
        ((float4*)xs)[t] = ((const float4*)(x + (size_t)tok * DIM))[t];
        __syncthreads();

        // GEMV1: h[ch] = sum_d x[d] * W1[sel][d][ch]; split d-range across 2 half-blocks
        const int ch   = t & (HID - 1);
        const int half = t >> 7;                  // 0 or 1
        const float* __restrict__ w1 = W1 + (size_t)sel * DIM * HID + ch;
        float acc = 0.0f;
        const int d0 = half * (DIM / 2);
        #pragma unroll 8
        for (int d = d0; d < d0 + DIM / 2; ++d) acc = fmaf(xs[d], w1[(size_t)d * HID], acc);
        part[t] = acc;
        __syncthreads();

        // combine halves + bias; LayerNorm reduce over 128 channels (2 waves)
        if (t < HID) {
            float h = part[t] + part[t + HID] + b1[sel * HID + t];
            rbuf[t] = h;
            float s = h, sq = h * h;
            #pragma unroll
            for (int off = 32; off > 0; off >>= 1) {
                s  += __shfl_down(s, off);
                sq += __shfl_down(sq, off);
            }
            if ((t & 63) == 0) { red[(t >> 6) * 2] = s; red[(t >> 6) * 2 + 1] = sq; }
        }
        __syncthreads();
        if (t < HID) {
            const float mu  = (red[0] + red[2]) * (1.0f / HID);
            const float msq = (red[1] + red[3]) * (1.0f / HID);
            const float inv = rsqrtf(msq - mu * mu + EPS);
            float r = (rbuf[t] - mu) * inv * gamma[sel * HID + t] + beta[sel * HID + t];
            rbuf[t] = fmaxf(r, 0.0f);
        }
        __syncthreads();

        // GEMV2: out[f] = sum_h rbuf[h] * W2[sel][h][f] + b2[sel][f]
        if (t < FPC_) {
            const float* __restrict__ w2 = W2 + (size_t)sel * HID * FPC_ + t;
            float o = b2[sel * FPC_ + t];
            #pragma unroll 8
            for (int h = 0; h < HID; ++h) o = fmaf(rbuf[h], w2[(size_t)h * FPC_], o);
            obuf[t] = o;
        }
        __syncthreads();
    }

    // --- write full row: zeros everywhere, expert block substituted per-float4
    float4* __restrict__ orow = (float4*)(out + (size_t)tok * FTOT);
    const int blk_lo = sel * (FPC_ / 4);          // first float4 index of expert block
    #pragma unroll
    for (int k = 0; k < 2; ++k) {
        const int p = t + k * 256;                // float4 index in row, 0..511
        float4 v = make_float4(0.f, 0.f, 0.f, 0.f);
        if (selected && p >= blk_lo && p < blk_lo + (FPC_ / 4)) {
            const int q = (p - blk_lo) * 4;
            v = make_float4(obuf[q], obuf[q + 1], obuf[q + 2], obuf[q + 3]);
        }
        orow[p] = v;
    }
}

extern "C" void kernel_launch(void* const* d_in, const int* in_sizes, int n_in,
                              void* d_out, int out_size, void* d_ws, size_t ws_size,
                              hipStream_t stream) {
    const float* x     = (const float*)d_in[0];
    const float* xc    = (const float*)d_in[1];
    const float* W1    = (const float*)d_in[2];
    const float* b1    = (const float*)d_in[3];
    const float* gamma = (const float*)d_in[4];
    const float* beta  = (const float*)d_in[5];
    const float* W2    = (const float*)d_in[6];
    const float* b2    = (const float*)d_in[7];
    float* out = (float*)d_out;

    int* sel_p = (int*)d_ws;

    hipMemsetAsync(sel_p, 0x7f, sizeof(int), stream);   // sel = huge
    clan_min_kernel<<<N_TOK / 256, 256, 0, stream>>>(xc, sel_p);
    fused_fill_expert_kernel<<<N_TOK, 256, 0, stream>>>(
        x, xc, W1, b1, gamma, beta, W2, b2, sel_p, out);
}